// Round 4
// baseline (585.004 us; speedup 1.0000x reference)
//
#include <hip/hip_runtime.h>
#include <hip/hip_bf16.h>
#include <cstdint>

// Problem constants (B,C,H,W fixed by setup_inputs)
constexpr int NB = 4;
constexpr int NC = 64;
constexpr int NH = 96;
constexpr int NW = 256;
constexpr int HWp = NH * NW;          // 24576 pixels per plane
constexpr float EPS = 1e-6f;

typedef __attribute__((ext_vector_type(8))) short short8;
typedef __attribute__((ext_vector_type(4))) short short4t;
typedef __attribute__((ext_vector_type(4))) float f32x4;

static __device__ __forceinline__ short f2bf(float f) {
    __hip_bfloat16 h = __float2bfloat16(f);
    return *reinterpret_cast<short*>(&h);
}

// ---------------------------------------------------------------------------
// LayerNorm2d over channels at each (b,h,w) + fused rect row-sums.
// BOTH sides in one launch (grid (NH, 2*NB)); per-row full sum + 8 edge
// partials produced via a 32KB XOR-swizzled LDS transpose.
// ---------------------------------------------------------------------------
__global__ __launch_bounds__(256) void k_ln(const float* __restrict__ x_l,
                                            const float* __restrict__ x_r,
                                            const float* __restrict__ gl,
                                            const float* __restrict__ bl,
                                            const float* __restrict__ gr,
                                            const float* __restrict__ br,
                                            short* __restrict__ XBl,
                                            short* __restrict__ XBr,
                                            float* __restrict__ R) {
    const int h = blockIdx.x, sideb = blockIdx.y;
    const int side = sideb >> 2, b = sideb & 3;
    const float* x = side ? x_r : x_l;
    const float* g = side ? gr : gl;
    const float* bta = side ? br : bl;
    short* XB = side ? XBr : XBl;
    const int t = threadIdx.x;                 // = w
    __shared__ float xm[32 * 256];             // 32 KB transpose scratch

    const float* xp = x + ((size_t)b * NC * NH + h) * NW + t;
    float v[64];
    float s = 0.f, sq = 0.f;
#pragma unroll
    for (int c = 0; c < 64; ++c) {
        float tv = xp[(size_t)c * HWp];
        v[c] = tv; s += tv; sq += tv * tv;
    }
    float mu = s * (1.f / 64.f);
    float var = sq * (1.f / 64.f) - mu * mu;
    float rs = rsqrtf(var + EPS);
#pragma unroll
    for (int c = 0; c < 64; ++c) v[c] = (v[c] - mu) * rs * g[c] + bta[c];

    // bf16 XB[b][chunk][h][w][16ci] (unchanged layout for k_convm)
#pragma unroll
    for (int chunk = 0; chunk < 4; ++chunk) {
        short8 s0, s1;
#pragma unroll
        for (int j = 0; j < 8; ++j) {
            s0[j] = f2bf(v[chunk * 16 + j]);
            s1[j] = f2bf(v[chunk * 16 + 8 + j]);
        }
        short* xb = XB + (((size_t)(b * 4 + chunk) * NH + h) * NW + t) * 16;
        *(short8*)xb = s0;
        *(short8*)(xb + 8) = s1;
    }

    // Row-sum + edge partials via LDS transpose, 2 passes of 32 channels.
#pragma unroll
    for (int p = 0; p < 2; ++p) {
        const int cbase = p * 32;
        __syncthreads();                       // guard xm reuse across passes
#pragma unroll
        for (int c = 0; c < 32; ++c)
            xm[c * 256 + (((t >> 2) ^ (c & 7)) << 2) + (t & 3)] = v[cbase + c];
        __syncthreads();
        const int cc = t & 31, q = t >> 5;     // 8 threads per channel
        float rsum = 0.f;
        float4 fs0 = {0,0,0,0}, fs1 = {0,0,0,0}, ls0 = {0,0,0,0}, ls1 = {0,0,0,0};
#pragma unroll
        for (int i = 0; i < 8; ++i) {
            int j4 = q * 8 + i;
            float4 f = *(const float4*)&xm[cc * 256 + ((j4 ^ (cc & 7)) << 2)];
            rsum += (f.x + f.y) + (f.z + f.w);
            if (i == 0) fs0 = f;               // px 0..3   (valid when q==0)
            if (i == 1) fs1 = f;               // px 4..7
            if (i == 6) ls0 = f;               // px 248..251 (valid when q==7)
            if (i == 7) ls1 = f;               // px 252..255
        }
        __syncthreads();                       // all reads done -> reuse xm
        xm[cc * 8 + q] = rsum;                 // eighth-partials at words 0..255
        if (q == 7) {                          // last-8 px at words 256..511
            *(float4*)&xm[256 + cc * 8] = ls0;
            *(float4*)&xm[256 + cc * 8 + 4] = ls1;
        }
        __syncthreads();
        if (t < 32) {                          // t<32 => q==0 => fs0/fs1 valid
            const int c = t;
            float full = 0.f;
#pragma unroll
            for (int q2 = 0; q2 < 8; ++q2) full += xm[c * 8 + q2];
            float h0 = xm[256 + c * 8 + 0], h1 = xm[256 + c * 8 + 1];
            float h2 = xm[256 + c * 8 + 2], h3 = xm[256 + c * 8 + 3];
            float h4 = xm[256 + c * 8 + 4], h5 = xm[256 + c * 8 + 5];
            float h6 = xm[256 + c * 8 + 6], h7 = xm[256 + c * 8 + 7];
            float e2 = fs0.x + fs0.y;
            float e4 = e2 + fs0.z + fs0.w;
            float e6 = e4 + fs1.x + fs1.y;
            float e8 = e6 + fs1.z + fs1.w;
            float r2 = h6 + h7;
            float r4 = (h4 + h5) + r2;
            float r6 = r4 + (h2 + h3);
            float r8 = r6 + (h0 + h1);
            float* Rp = R + ((size_t)(sideb * 64 + cbase + c) * NH + h) * 9;
            Rp[0] = full; Rp[1] = e2; Rp[2] = e4; Rp[3] = e6; Rp[4] = e8;
            Rp[5] = r2;  Rp[6] = r4; Rp[7] = r6; Rp[8] = r8;
        }
    }
}

// ---------------------------------------------------------------------------
// R9: k_mid = fused comb + z + sel2. One block per (side,b), 256 threads.
// Phase A: rect sums from R (LDS-staged in 8 passes of 8 channels) -> Tl.
// Phase B: Z[c] = (1/HW)*sum_m dot(dw[m,c,:],Tl[m,:]) + sum_m db[m,c].
// Phase C: S=relu(Z@c1w^T+c1b); P=S@pw; softmax -> SW, QB.
// Replaces 3 latency-bound launches (k_comb, k_z, k_sel2).
// ---------------------------------------------------------------------------
__global__ __launch_bounds__(256) void k_mid(const float* __restrict__ R,
                                             const float* __restrict__ l_dw,
                                             const float* __restrict__ r_dw,
                                             const float* __restrict__ l_db,
                                             const float* __restrict__ r_db,
                                             const float* __restrict__ l_c1w,
                                             const float* __restrict__ r_c1w,
                                             const float* __restrict__ l_c1b,
                                             const float* __restrict__ r_c1b,
                                             const float* __restrict__ l_pw,
                                             const float* __restrict__ r_pw,
                                             float* __restrict__ Sw,
                                             float* __restrict__ Qb) {
    const int sideb = blockIdx.x;              // side*4 + b
    const int side = sideb >> 2;
    const float* dw  = side ? r_dw  : l_dw;
    const float* db  = side ? r_db  : l_db;
    const float* c1w = side ? r_c1w : l_c1w;
    const float* c1b = side ? r_c1b : l_c1b;
    const float* pw  = side ? r_pw  : l_pw;
    const int t = threadIdx.x, lane = t & 63, wv = t >> 6;

    __shared__ float smem[11200];              // 44.8 KB
    float* region1 = smem;                     // rs (8*869) then cw (8192)
    float* Tl   = smem + 8192;                 // 2304: [m][ci*9+k9]
    float* zred = Tl + 2304;                   // 256
    float* zs   = zred + 256;                  // 64
    float* ss   = zs + 64;                     // 128
    float* swl  = ss + 128;                    // 256

    // ---- Phase A: rect sums (8 passes of 8 channels) ----
    const float* Rbase = R + (size_t)(sideb * 64) * NH * 9;
    for (int cg = 0; cg < 8; ++cg) {
        __syncthreads();                       // prior pass reads done
        for (int i = t; i < 8 * 864; i += 256) {
            int ci8 = i / 864, rem = i - ci8 * 864;
            region1[ci8 * 869 + rem] = Rbase[(size_t)(cg * 8 + ci8) * 864 + rem];
        }
        __syncthreads();
        for (int tau = t; tau < 288; tau += 256) {
            int ci8 = tau / 36, tap = tau % 36;
            int m = tap / 9, kh = (tap % 9) / 3, kw = tap % 3;
            int d = 2 * (m + 1);
            int r0 = (kh == 2) ? d : 0;
            int r1 = (kh == 0) ? NH - d : NH;
            const float* rp = region1 + ci8 * 869;
            float s = 0.f;
            for (int r = r0; r < r1; ++r) {
                float rowv = rp[r * 9];
                if (kw == 0) rowv -= rp[r * 9 + 5 + m];
                else if (kw == 2) rowv -= rp[r * 9 + 1 + m];
                s += rowv;
            }
            Tl[m * 576 + (cg * 8 + ci8) * 9 + kh * 3 + kw] = s;
        }
    }
    __syncthreads();

    // ---- Phase B: Z ----
    {
        const int m = t >> 6, c = t & 63;
        const float* wp = dw + (size_t)(m * 64 + c) * 576;
        const float* tp = Tl + m * 576;
        float s = 0.f;
        for (int j = 0; j < 576; ++j) s += wp[j] * tp[j];
        zred[m * 64 + c] = s;
    }
    __syncthreads();
    if (t < 64) {
        float z = (zred[t] + zred[64 + t]) + (zred[128 + t] + zred[192 + t]);
        float bias = db[t] + db[64 + t] + db[128 + t] + db[192 + t];
        zs[t] = z * (1.f / (float)HWp) + bias;
    }
    __syncthreads();                           // zs ready; region1 now dead

    // ---- Phase C: selection MLP + softmax ----
    for (int i = t; i < 8192; i += 256) region1[i] = c1w[i];
    __syncthreads();
    if (t < 128) {
        float s = c1b[t];
        const float* wrow = region1 + t * 64;
        for (int c = 0; c < 64; ++c) s += zs[c] * wrow[c];
        ss[t] = fmaxf(s, 0.f);
    }
    __syncthreads();
    float p = 0.f;
    for (int j = 0; j < 128; ++j) p += ss[j] * pw[j * 256 + t];
    float mx = p;
#pragma unroll
    for (int o = 32; o; o >>= 1) mx = fmaxf(mx, __shfl_xor(mx, o, 64));
    float e = __expf(p - mx);
    float sum = e;
#pragma unroll
    for (int o = 32; o; o >>= 1) sum += __shfl_xor(sum, o, 64);
    float swv = e / sum;
    Sw[(sideb * 4 + wv) * 64 + lane] = swv;
    swl[wv * 64 + lane] = swv;
    __syncthreads();
    if (t < 64) {
        float qb = swl[t] * db[t] + swl[64 + t] * db[64 + t]
                 + swl[128 + t] * db[128 + t] + swl[192 + t] * db[192 + t];
        Qb[sideb * 64 + t] = qb;
    }
}

// ---------------------------------------------------------------------------
// Fold Sw into conv weights, bf16, MFMA B-fragment order. Merged (4608 blks).
// ---------------------------------------------------------------------------
__global__ __launch_bounds__(256) void k_fold(const float* __restrict__ l_dw,
                                              const float* __restrict__ r_dw,
                                              const float* __restrict__ Sw,
                                              short* __restrict__ WB) {
    int bx = blockIdx.x;
    int side = (bx >= 2304) ? 1 : 0;
    int idx = (bx - side * 2304) * 256 + threadIdx.x;   // 589824 per side
    const float* dw = side ? r_dw : l_dw;
    short* wbs = WB + (size_t)side * 589824;
    int kk = idx & 31;
    int co = (idx >> 5) & 63;
    int rest = idx >> 11;            // [0,288)
    int tpair = rest % 18;
    int bc = rest / 18;              // [0,16)
    int chunk = bc & 3, b = bc >> 2;
    int tpl = kk >> 4, cil = kk & 15;
    int tap = 2 * tpair + tpl;
    int m = tap / 9, k9 = tap % 9;
    int ci = chunk * 16 + cil;
    float val = Sw[((side * 4 + b) * 4 + m) * 64 + co]
              * dw[(size_t)((m * 64 + co) * 64 + ci) * 9 + k9];
    wbs[idx] = f2bf(val);
}

// ---------------------------------------------------------------------------
// MFMA implicit-GEMM fused 4-dilation conv -> Q (bf16 NHWC).
// R9: tp loop FULLY unrolled. The rolled loop issued each iteration's 4
// global weight loads only after the previous iteration's MFMAs (in-order),
// so every iteration ate a full ~200cyc L2 latency: 40cyc MFMA / 200cyc =
// the observed 19% MfmaUtil. Full unroll folds the /9 %9 divisions to
// constants (VALU down) and lets the scheduler hoist weight loads across
// iterations with counted vmcnt.
// ---------------------------------------------------------------------------
__global__ __launch_bounds__(256) void k_convm(const short* __restrict__ XBl,
                                               const short* __restrict__ XBr,
                                               const short* __restrict__ WBa,
                                               const float* __restrict__ QBa,
                                               short* __restrict__ QLs,
                                               short* __restrict__ QRs) {
    const int wt = blockIdx.x, h = blockIdx.y;
    const int side = blockIdx.z >> 2, b = blockIdx.z & 3;
    const short* XB = side ? XBr : XBl;
    const short* WB = WBa + (size_t)side * 589824;
    const float* Qb = QBa + side * 256;
    short* Qs = side ? QRs : QLs;
    const int t = threadIdx.x;
    const int lane = t & 63, wave = t >> 6;
    const int g = lane >> 4, ln15 = lane & 15;
    __shared__ short tile[2 * 9 * 144 * 8];   // [half][r][col][ci8]

    f32x4 acc[2][4];
    {
        float qb[4];
#pragma unroll
        for (int nt = 0; nt < 4; ++nt) qb[nt] = Qb[b * 64 + nt * 16 + ln15];
#pragma unroll
        for (int mt = 0; mt < 2; ++mt)
#pragma unroll
            for (int nt = 0; nt < 4; ++nt)
                acc[mt][nt] = (f32x4){qb[nt], qb[nt], qb[nt], qb[nt]};
    }
    const int w0 = wt * 128;
    const int laneelem = (wave * 32 + ln15) * 8;
    const int halfoff = (g & 1) * (9 * 144 * 8);
    const int tsel = g >> 1;

    // register staging buffer: 6 slots x 2 halves
    short8 pv[6][2];
    auto LOADC = [&](int chunk) {
        const short* src = XB + (size_t)(b * 4 + chunk) * NH * NW * 16;
#pragma unroll
        for (int i = 0; i < 6; ++i) {
            const int slot = t + i * 256;
            const bool live = (i < 5) || (t < 16);   // 1296 = 5*256 + 16
            short8 z = {0, 0, 0, 0, 0, 0, 0, 0};
            pv[i][0] = z; pv[i][1] = z;
            if (live) {
                int r = slot / 144, col = slot % 144;
                int gh = h + 2 * r - 8;
                int gw = w0 - 8 + col;
                if (gh >= 0 && gh < NH && gw >= 0 && gw < NW) {
                    const short* p = src + ((size_t)gh * NW + gw) * 16;
                    pv[i][0] = *(const short8*)p;
                    pv[i][1] = *(const short8*)(p + 8);
                }
            }
        }
    };

    LOADC(0);
    for (int chunk = 0; chunk < 4; ++chunk) {
        // barrier #1: previous chunk's ds_reads all consumed -> safe to
        // overwrite tile.
        __builtin_amdgcn_s_barrier();
        __builtin_amdgcn_sched_barrier(0);
#pragma unroll
        for (int i = 0; i < 6; ++i) {
            const int slot = t + i * 256;
            const bool live = (i < 5) || (t < 16);
            if (live) {
                *(short8*)(tile + slot * 8) = pv[i][0];
                *(short8*)(tile + (9 * 144 + slot) * 8) = pv[i][1];
            }
        }
        if (chunk < 3) LOADC(chunk + 1);   // prefetch: vmcnt stays in flight
        asm volatile("s_waitcnt lgkmcnt(0)" ::: "memory");  // ds_writes visible
        __builtin_amdgcn_s_barrier();      // barrier #2: tile ready
        __builtin_amdgcn_sched_barrier(0);

        const short* wbase = WB + (size_t)((b * 4 + chunk) * 18) * 2048 + ln15 * 32 + g * 8;
#pragma unroll
        for (int tp = 0; tp < 18; ++tp) {
            const int ta = 2 * tp, tb = ta + 1;
            const int ma = ta / 9, k9a = ta % 9;
            const int mb = tb / 9, k9b = tb % 9;
            const int offA = ((4 + (ma + 1) * (k9a / 3 - 1)) * 144 + 8 + 2 * (ma + 1) * (k9a % 3 - 1)) * 8;
            const int offB = ((4 + (mb + 1) * (k9b / 3 - 1)) * 144 + 8 + 2 * (mb + 1) * (k9b % 3 - 1)) * 8;
            const int aoff = (tsel ? offB : offA) + laneelem + halfoff;
            const short* bp = wbase + (size_t)tp * 2048;
            short8 b0 = *(const short8*)(bp);
            short8 b1 = *(const short8*)(bp + 512);
            short8 b2 = *(const short8*)(bp + 1024);
            short8 b3 = *(const short8*)(bp + 1536);
            const short* ap = tile + aoff;
            short8 a0 = *(const short8*)(ap);
            short8 a1 = *(const short8*)(ap + 128);
            acc[0][0] = __builtin_amdgcn_mfma_f32_16x16x32_bf16(a0, b0, acc[0][0], 0, 0, 0);
            acc[0][1] = __builtin_amdgcn_mfma_f32_16x16x32_bf16(a0, b1, acc[0][1], 0, 0, 0);
            acc[0][2] = __builtin_amdgcn_mfma_f32_16x16x32_bf16(a0, b2, acc[0][2], 0, 0, 0);
            acc[0][3] = __builtin_amdgcn_mfma_f32_16x16x32_bf16(a0, b3, acc[0][3], 0, 0, 0);
            acc[1][0] = __builtin_amdgcn_mfma_f32_16x16x32_bf16(a1, b0, acc[1][0], 0, 0, 0);
            acc[1][1] = __builtin_amdgcn_mfma_f32_16x16x32_bf16(a1, b1, acc[1][1], 0, 0, 0);
            acc[1][2] = __builtin_amdgcn_mfma_f32_16x16x32_bf16(a1, b2, acc[1][2], 0, 0, 0);
            acc[1][3] = __builtin_amdgcn_mfma_f32_16x16x32_bf16(a1, b3, acc[1][3], 0, 0, 0);
        }
    }
    // epilogue: D row=(lane>>4)*4+j (px), col=lane&15 (co); store bf16 NHWC
#pragma unroll
    for (int mt = 0; mt < 2; ++mt) {
        int px = w0 + wave * 32 + mt * 16 + g * 4;
#pragma unroll
        for (int j = 0; j < 4; ++j) {
            short* qp = Qs + ((size_t)(b * NH + h) * NW + px + j) * 64 + ln15;
            qp[0]  = f2bf(acc[mt][0][j]);
            qp[16] = f2bf(acc[mt][1][j]);
            qp[32] = f2bf(acc[mt][2][j]);
            qp[48] = f2bf(acc[mt][3][j]);
        }
    }
}

// ---------------------------------------------------------------------------
// 1x1 conv V = x @ w2^T + b2, output bf16 "NCHW w-permuted": per 64-w tile,
// VT[b][c][h][wt*64 + s] = V[wt*64 + u(s)][c],  u(s) = (s>>2) + 16*(s&3).
// Both sides in one launch (blockIdx.z in [0, 2*NB)).
// ---------------------------------------------------------------------------
__global__ __launch_bounds__(256) void k_v(const float* __restrict__ x_l,
                                           const float* __restrict__ x_r,
                                           const float* __restrict__ w2l,
                                           const float* __restrict__ b2l,
                                           const float* __restrict__ w2r,
                                           const float* __restrict__ b2r,
                                           short* __restrict__ VL,
                                           short* __restrict__ VR) {
    int wt = blockIdx.x, h = blockIdx.y;
    int side = blockIdx.z >> 2, b = blockIdx.z & 3;
    const float* x  = side ? x_r : x_l;
    const float* w2 = side ? w2r : w2l;
    const float* b2 = side ? b2r : b2l;
    short* VT = side ? VR : VL;
    int t = threadIdx.x, lane = t & 63, q = t >> 6;
    __shared__ float xs[64 * 68];    // [ci][px] then reused as [c][px]
    __shared__ float w2t[64 * 68];   // [ci][c]
    int w0 = wt * 64;
    const float* src = x + (size_t)(b * 64) * HWp + h * NW + w0;
    for (int idx = t; idx < 4096; idx += 256) {
        int ci = idx >> 6, col = idx & 63;
        xs[ci * 68 + col] = src[(size_t)ci * HWp + col];
    }
    for (int idx = t; idx < 4096; idx += 256) {
        int co = idx >> 6, ci = idx & 63;
        w2t[ci * 68 + co] = w2[co * 64 + ci];
    }
    __syncthreads();

    const int pl0 = (lane & 15) * 4;            // 4 px per thread
    const int c0 = q * 16 + (lane >> 4) * 4;    // 4 c per thread
    f32x4 a4[4];
#pragma unroll
    for (int cc = 0; cc < 4; ++cc) {
        float bb = b2[c0 + cc];
        a4[cc] = (f32x4){bb, bb, bb, bb};
    }
    for (int ci = 0; ci < 64; ++ci) {
        f32x4 xv = *(const f32x4*)(xs + ci * 68 + pl0);
        f32x4 wv = *(const f32x4*)(w2t + ci * 68 + c0);
        a4[0] += xv * wv[0];
        a4[1] += xv * wv[1];
        a4[2] += xv * wv[2];
        a4[3] += xv * wv[3];
    }
    __syncthreads();
#pragma unroll
    for (int cc = 0; cc < 4; ++cc)
        *(f32x4*)(xs + (c0 + cc) * 68 + pl0) = a4[cc];
    __syncthreads();
    {
        int s = t & 63, g2 = t >> 6;
        int u = (s >> 2) + 16 * (s & 3);
#pragma unroll
        for (int cc = 0; cc < 16; ++cc) {
            int ch = g2 * 16 + cc;
            VT[((size_t)(b * 64 + ch) * NH + h) * NW + w0 + s] = f2bf(xs[ch * 68 + u]);
        }
    }
}

// ---------------------------------------------------------------------------
// Fused cross-attention, flash-style, both QK^T and PV on MFMA.
// Wave owns 32 q-rows; grid (4, NH, 2*NB) = 6144 blocks.
// ---------------------------------------------------------------------------
__global__ __launch_bounds__(128, 2) void k_attn(const short* __restrict__ QL,
                                                 const short* __restrict__ QR,
                                                 const short* __restrict__ VL,
                                                 const short* __restrict__ VR,
                                                 const float* __restrict__ x_l,
                                                 const float* __restrict__ x_r,
                                                 const float* __restrict__ beta,
                                                 const float* __restrict__ gamma,
                                                 float* __restrict__ out_all) {
    const int bx = blockIdx.x, h = blockIdx.y;
    const int side = blockIdx.z >> 2, b = blockIdx.z & 3;
    constexpr size_t PLANE = (size_t)NB * NC * NH * NW;
    const short* Qa  = side ? QR : QL;
    const short* Qbp = side ? QL : QR;
    const short* VT  = side ? VL : VR;
    const float* xres = side ? x_r : x_l;
    const float* scl  = side ? gamma : beta;
    float* out = out_all + (side ? PLANE : 0);

    const int t = threadIdx.x, lane = t & 63, wave = t >> 6;
    const int q = lane >> 4, c15 = lane & 15;
    __shared__ __align__(16) short PB[2][32 * 72];
    short* pb = PB[wave];

    const int wbase = bx * 64 + wave * 32;
    const short* qabase = Qa + ((size_t)(b * NH + h) * NW + wbase) * 64;
    const short* qbbase = Qbp + ((size_t)(b * NH + h) * NW) * 64;

    short8 afrag[2][2];
#pragma unroll
    for (int mt = 0; mt < 2; ++mt)
#pragma unroll
        for (int kk = 0; kk < 2; ++kk)
            afrag[mt][kk] = *(const short8*)(qabase + (mt * 16 + c15) * 64 + kk * 32 + q * 8);

    f32x4 osum[2][4];
#pragma unroll
    for (int mt = 0; mt < 2; ++mt)
#pragma unroll
        for (int nt = 0; nt < 4; ++nt) osum[mt][nt] = (f32x4){0.f, 0.f, 0.f, 0.f};
    float mrow[8], lrow[8];
#pragma unroll
    for (int i = 0; i < 8; ++i) { mrow[i] = -1e30f; lrow[i] = 0.f; }

    for (int vt = 0; vt < 4; ++vt) {
        f32x4 s[2][4];
#pragma unroll
        for (int mt = 0; mt < 2; ++mt)
#pragma unroll
            for (int nt = 0; nt < 4; ++nt) s[mt][nt] = (f32x4){0.f, 0.f, 0.f, 0.f};
#pragma unroll
        for (int kk = 0; kk < 2; ++kk) {
            short8 bq[4];
#pragma unroll
            for (int nt = 0; nt < 4; ++nt)
                bq[nt] = *(const short8*)(qbbase + (size_t)(vt * 64 + nt * 16 + c15) * 64 + kk * 32 + q * 8);
#pragma unroll
            for (int mt = 0; mt < 2; ++mt)
#pragma unroll
                for (int nt = 0; nt < 4; ++nt)
                    s[mt][nt] = __builtin_amdgcn_mfma_f32_16x16x32_bf16(afrag[mt][kk], bq[nt], s[mt][nt], 0, 0, 0);
        }
#pragma unroll
        for (int mt = 0; mt < 2; ++mt)
#pragma unroll
            for (int nt = 0; nt < 4; ++nt)
#pragma unroll
                for (int r = 0; r < 4; ++r) s[mt][nt][r] *= 0.125f;
        float al[8];
#pragma unroll
        for (int mt = 0; mt < 2; ++mt)
#pragma unroll
            for (int r = 0; r < 4; ++r) {
                float m0 = fmaxf(fmaxf(s[mt][0][r], s[mt][1][r]), fmaxf(s[mt][2][r], s[mt][3][r]));
#pragma unroll
                for (int msk = 1; msk < 16; msk <<= 1) m0 = fmaxf(m0, __shfl_xor(m0, msk, 64));
                int i = mt * 4 + r;
                float mn = fmaxf(mrow[i], m0);
                al[i] = __expf(mrow[i] - mn);
                mrow[i] = mn;
            }
#pragma unroll
        for (int mt = 0; mt < 2; ++mt)
#pragma unroll
            for (int r = 0; r < 4; ++r) {
                int i = mt * 4 + r;
                float m = mrow[i];
                float p0 = __expf(s[mt][0][r] - m);
                float p1 = __expf(s[mt][1][r] - m);
                float p2 = __expf(s[mt][2][r] - m);
                float p3 = __expf(s[mt][3][r] - m);
                short4t pk = {f2bf(p0), f2bf(p1), f2bf(p2), f2bf(p3)};
                *(short4t*)(pb + (mt * 16 + q * 4 + r) * 72 + c15 * 4) = pk;
                float lsv = (p0 + p1) + (p2 + p3);
#pragma unroll
                for (int msk = 1; msk < 16; msk <<= 1) lsv += __shfl_xor(lsv, msk, 64);
                lrow[i] = lrow[i] * al[i] + lsv;
            }
#pragma unroll
        for (int mt = 0; mt < 2; ++mt)
#pragma unroll
            for (int nt = 0; nt < 4; ++nt)
#pragma unroll
                for (int r = 0; r < 4; ++r) osum[mt][nt][r] *= al[mt * 4 + r];
#pragma unroll
        for (int kk = 0; kk < 2; ++kk) {
            short8 ap[2], bv[4];
#pragma unroll
            for (int mt = 0; mt < 2; ++mt)
                ap[mt] = *(const short8*)(pb + (mt * 16 + c15) * 72 + kk * 32 + q * 8);
#pragma unroll
            for (int nt = 0; nt < 4; ++nt)
                bv[nt] = *(const short8*)(VT + ((size_t)(b * 64 + nt * 16 + c15) * NH + h) * NW + vt * 64 + kk * 32 + q * 8);
#pragma unroll
            for (int mt = 0; mt < 2; ++mt)
#pragma unroll
                for (int nt = 0; nt < 4; ++nt)
                    osum[mt][nt] = __builtin_amdgcn_mfma_f32_16x16x32_bf16(ap[mt], bv[nt], osum[mt][nt], 0, 0, 0);
        }
    }
    float linv[8];
#pragma unroll
    for (int i = 0; i < 8; ++i) linv[i] = 1.f / lrow[i];
#pragma unroll
    for (int nt = 0; nt < 4; ++nt) {
        int c = nt * 16 + c15;
        float bv = scl[c];
        size_t pbase = ((size_t)(b * 64 + c) * NH + h) * NW + wbase;
#pragma unroll
        for (int mt = 0; mt < 2; ++mt)
#pragma unroll
            for (int r = 0; r < 4; ++r) {
                size_t o = pbase + mt * 16 + q * 4 + r;
                out[o] = xres[o] + osum[mt][nt][r] * linv[mt * 4 + r] * bv;
            }
    }
}

// ---------------------------------------------------------------------------
extern "C" void kernel_launch(void* const* d_in, const int* in_sizes, int n_in,
                              void* d_out, int out_size, void* d_ws, size_t ws_size,
                              hipStream_t stream) {
    const float* x_l   = (const float*)d_in[0];
    const float* x_r   = (const float*)d_in[1];
    const float* lnl_g = (const float*)d_in[2];
    const float* lnl_b = (const float*)d_in[3];
    const float* lnr_g = (const float*)d_in[4];
    const float* lnr_b = (const float*)d_in[5];
    const float* l_dw  = (const float*)d_in[6];
    const float* l_db  = (const float*)d_in[7];
    const float* l_c1w = (const float*)d_in[8];
    const float* l_c1b = (const float*)d_in[9];
    const float* l_pw  = (const float*)d_in[10];
    const float* r_dw  = (const float*)d_in[11];
    const float* r_db  = (const float*)d_in[12];
    const float* r_c1w = (const float*)d_in[13];
    const float* r_c1b = (const float*)d_in[14];
    const float* r_pw  = (const float*)d_in[15];
    const float* l2w   = (const float*)d_in[16];
    const float* l2b   = (const float*)d_in[17];
    const float* r2w   = (const float*)d_in[18];
    const float* r2b   = (const float*)d_in[19];
    const float* beta  = (const float*)d_in[20];
    const float* gamma = (const float*)d_in[21];
    float* out = (float*)d_out;

    constexpr size_t PLANE = (size_t)NB * NC * NH * NW;   // 6291456
    float* ws = (float*)d_ws;
    short* XBl = (short*)ws;         ws += PLANE / 2;     // bf16 [b][chunk][h][w][16]
    short* XBr = (short*)ws;         ws += PLANE / 2;
    short* QLs = (short*)ws;         ws += PLANE / 2;
    short* QRs = (short*)ws;         ws += PLANE / 2;
    short* VLs = (short*)ws;         ws += PLANE / 2;
    short* VRs = (short*)ws;         ws += PLANE / 2;
    short* WB  = (short*)ws;         ws += 589824;        // 2 x 589824 bf16
    float* Rb  = ws;                 ws += 442368;        // 2*4*64*96*9
    float* SW  = ws;                 ws += 2048;
    float* QB  = ws;                 ws += 512;

    dim3 blk(256);
    k_ln    <<<dim3(NH, 2 * NB), blk, 0, stream>>>(x_l, x_r, lnl_g, lnl_b, lnr_g, lnr_b,
                                                   XBl, XBr, Rb);
    k_mid   <<<dim3(8), blk, 0, stream>>>(Rb, l_dw, r_dw, l_db, r_db,
                                          l_c1w, r_c1w, l_c1b, r_c1b, l_pw, r_pw,
                                          SW, QB);
    k_fold  <<<dim3(4608), blk, 0, stream>>>(l_dw, r_dw, SW, WB);
    k_convm <<<dim3(2, NH, 2 * NB), blk, 0, stream>>>(XBl, XBr, WB, QB, QLs, QRs);
    k_v     <<<dim3(4, NH, 2 * NB), blk, 0, stream>>>(x_l, x_r, l2w, l2b, r2w, r2b, VLs, VRs);
    k_attn  <<<dim3(4, NH, 2 * NB), dim3(128), 0, stream>>>(QLs, QRs, VLs, VRs,
                                                            x_l, x_r, beta, gamma, out);
}

// Round 5
// 374.404 us; speedup vs baseline: 1.5625x; 1.5625x over previous
//
#include <hip/hip_runtime.h>
#include <hip/hip_bf16.h>
#include <cstdint>

// Problem constants (B,C,H,W fixed by setup_inputs)
constexpr int NB = 4;
constexpr int NC = 64;
constexpr int NH = 96;
constexpr int NW = 256;
constexpr int HWp = NH * NW;          // 24576 pixels per plane
constexpr float EPS = 1e-6f;

typedef __attribute__((ext_vector_type(8))) short short8;
typedef __attribute__((ext_vector_type(4))) short short4t;
typedef __attribute__((ext_vector_type(4))) float f32x4;

static __device__ __forceinline__ short f2bf(float f) {
    __hip_bfloat16 h = __float2bfloat16(f);
    return *reinterpret_cast<short*>(&h);
}

// ---------------------------------------------------------------------------
// R10: k_lnv = grid-fused LayerNorm(+rect row-sums) AND 1x1-conv V.
// Both consume only kernel inputs and write disjoint buffers -> truly
// independent; fusing them into ONE launch (grid (5, NH, 2*NB)) lets the
// two latency-bound kernels co-schedule. blockIdx.x==4 -> LN path (768
// blocks), else V path (3072 blocks). Block-uniform branch, union LDS.
// (R4 lesson: k_mid fused to 8 blocks -> 243us. Fusion must ADD blocks.)
// ---------------------------------------------------------------------------
__global__ __launch_bounds__(256) void k_lnv(const float* __restrict__ x_l,
                                             const float* __restrict__ x_r,
                                             const float* __restrict__ gl,
                                             const float* __restrict__ bl,
                                             const float* __restrict__ gr,
                                             const float* __restrict__ br,
                                             short* __restrict__ XBl,
                                             short* __restrict__ XBr,
                                             float* __restrict__ R,
                                             const float* __restrict__ w2l,
                                             const float* __restrict__ b2l,
                                             const float* __restrict__ w2r,
                                             const float* __restrict__ b2r,
                                             short* __restrict__ VL,
                                             short* __restrict__ VR) {
    __shared__ float smem[8704];               // union: LN 8192 / V 2x4352
    const int h = blockIdx.y, sideb = blockIdx.z;
    const int side = sideb >> 2, b = sideb & 3;
    const int t = threadIdx.x;

    if (blockIdx.x == 4) {
        // ================= LN + rect row-sums =================
        const float* x = side ? x_r : x_l;
        const float* g = side ? gr : gl;
        const float* bta = side ? br : bl;
        short* XB = side ? XBr : XBl;
        float* xm = smem;

        const float* xp = x + ((size_t)b * NC * NH + h) * NW + t;
        float v[64];
        float s = 0.f, sq = 0.f;
#pragma unroll
        for (int c = 0; c < 64; ++c) {
            float tv = xp[(size_t)c * HWp];
            v[c] = tv; s += tv; sq += tv * tv;
        }
        float mu = s * (1.f / 64.f);
        float var = sq * (1.f / 64.f) - mu * mu;
        float rs = rsqrtf(var + EPS);
#pragma unroll
        for (int c = 0; c < 64; ++c) v[c] = (v[c] - mu) * rs * g[c] + bta[c];

        // bf16 XB[b][chunk][h][w][16ci]
#pragma unroll
        for (int chunk = 0; chunk < 4; ++chunk) {
            short8 s0, s1;
#pragma unroll
            for (int j = 0; j < 8; ++j) {
                s0[j] = f2bf(v[chunk * 16 + j]);
                s1[j] = f2bf(v[chunk * 16 + 8 + j]);
            }
            short* xb = XB + (((size_t)(b * 4 + chunk) * NH + h) * NW + t) * 16;
            *(short8*)xb = s0;
            *(short8*)(xb + 8) = s1;
        }

        // Row-sum + edge partials via LDS transpose, 2 passes of 32 channels.
#pragma unroll
        for (int p = 0; p < 2; ++p) {
            const int cbase = p * 32;
            __syncthreads();
#pragma unroll
            for (int c = 0; c < 32; ++c)
                xm[c * 256 + (((t >> 2) ^ (c & 7)) << 2) + (t & 3)] = v[cbase + c];
            __syncthreads();
            const int cc = t & 31, q = t >> 5;
            float rsum = 0.f;
            float4 fs0 = {0,0,0,0}, fs1 = {0,0,0,0}, ls0 = {0,0,0,0}, ls1 = {0,0,0,0};
#pragma unroll
            for (int i = 0; i < 8; ++i) {
                int j4 = q * 8 + i;
                float4 f = *(const float4*)&xm[cc * 256 + ((j4 ^ (cc & 7)) << 2)];
                rsum += (f.x + f.y) + (f.z + f.w);
                if (i == 0) fs0 = f;
                if (i == 1) fs1 = f;
                if (i == 6) ls0 = f;
                if (i == 7) ls1 = f;
            }
            __syncthreads();
            xm[cc * 8 + q] = rsum;
            if (q == 7) {
                *(float4*)&xm[256 + cc * 8] = ls0;
                *(float4*)&xm[256 + cc * 8 + 4] = ls1;
            }
            __syncthreads();
            if (t < 32) {
                const int c = t;
                float full = 0.f;
#pragma unroll
                for (int q2 = 0; q2 < 8; ++q2) full += xm[c * 8 + q2];
                float h0 = xm[256 + c * 8 + 0], h1 = xm[256 + c * 8 + 1];
                float h2 = xm[256 + c * 8 + 2], h3 = xm[256 + c * 8 + 3];
                float h4 = xm[256 + c * 8 + 4], h5 = xm[256 + c * 8 + 5];
                float h6 = xm[256 + c * 8 + 6], h7 = xm[256 + c * 8 + 7];
                float e2 = fs0.x + fs0.y;
                float e4 = e2 + fs0.z + fs0.w;
                float e6 = e4 + fs1.x + fs1.y;
                float e8 = e6 + fs1.z + fs1.w;
                float r2 = h6 + h7;
                float r4 = (h4 + h5) + r2;
                float r6 = r4 + (h2 + h3);
                float r8 = r6 + (h0 + h1);
                float* Rp = R + ((size_t)(sideb * 64 + cbase + c) * NH + h) * 9;
                Rp[0] = full; Rp[1] = e2; Rp[2] = e4; Rp[3] = e6; Rp[4] = e8;
                Rp[5] = r2;  Rp[6] = r4; Rp[7] = r6; Rp[8] = r8;
            }
        }
    } else {
        // ================= 1x1 conv V =================
        const int wt = blockIdx.x;
        const float* x  = side ? x_r : x_l;
        const float* w2 = side ? w2r : w2l;
        const float* b2 = side ? b2r : b2l;
        short* VT = side ? VR : VL;
        const int lane = t & 63, q = t >> 6;
        float* xs  = smem;                     // [ci][px] then reused as [c][px]
        float* w2t = smem + 4352;              // [ci][c]
        int w0 = wt * 64;
        const float* src = x + (size_t)(b * 64) * HWp + h * NW + w0;
        for (int idx = t; idx < 4096; idx += 256) {
            int ci = idx >> 6, col = idx & 63;
            xs[ci * 68 + col] = src[(size_t)ci * HWp + col];
        }
        for (int idx = t; idx < 4096; idx += 256) {
            int co = idx >> 6, ci = idx & 63;
            w2t[ci * 68 + co] = w2[co * 64 + ci];
        }
        __syncthreads();

        const int pl0 = (lane & 15) * 4;
        const int c0 = q * 16 + (lane >> 4) * 4;
        f32x4 a4[4];
#pragma unroll
        for (int cc = 0; cc < 4; ++cc) {
            float bb = b2[c0 + cc];
            a4[cc] = (f32x4){bb, bb, bb, bb};
        }
        for (int ci = 0; ci < 64; ++ci) {
            f32x4 xv = *(const f32x4*)(xs + ci * 68 + pl0);
            f32x4 wv = *(const f32x4*)(w2t + ci * 68 + c0);
            a4[0] += xv * wv[0];
            a4[1] += xv * wv[1];
            a4[2] += xv * wv[2];
            a4[3] += xv * wv[3];
        }
        __syncthreads();
#pragma unroll
        for (int cc = 0; cc < 4; ++cc)
            *(f32x4*)(xs + (c0 + cc) * 68 + pl0) = a4[cc];
        __syncthreads();
        {
            int s = t & 63, g2 = t >> 6;
            int u = (s >> 2) + 16 * (s & 3);
#pragma unroll
            for (int cc = 0; cc < 16; ++cc) {
                int ch = g2 * 16 + cc;
                VT[((size_t)(b * 64 + ch) * NH + h) * NW + w0 + s] = f2bf(xs[ch * 68 + u]);
            }
        }
    }
}

// ---------------------------------------------------------------------------
// Combine per-row values into the 36 rect sums per (side,b,ci).
// ---------------------------------------------------------------------------
__global__ __launch_bounds__(128) void k_comb(const float* __restrict__ R,
                                              float* __restrict__ T) {
    int x = blockIdx.x;                        // side*256 + b*64 + ci
    int side = x >> 8, rem = x & 255, b = rem >> 6, ci = rem & 63;
    __shared__ float rp[NH][9];
    int t = threadIdx.x;
    const float* src = R + (size_t)x * NH * 9;
    for (int i = t; i < NH * 9; i += 128) ((float*)rp)[i] = src[i];
    __syncthreads();
    if (t < 36) {
        int m = t / 9, kh = (t % 9) / 3, kw = t % 3;
        int d = 2 * (m + 1);
        int r0 = (kh == 2) ? d : 0;
        int r1 = (kh == 0) ? NH - d : NH;
        float s = 0.f;
        for (int r = r0; r < r1; ++r) {
            float rowv = rp[r][0];
            if (kw == 0) rowv -= rp[r][5 + m];
            else if (kw == 2) rowv -= rp[r][1 + m];
            s += rowv;
        }
        T[side * 9216 + (b * 4 + m) * 576 + ci * 9 + kh * 3 + kw] = s;
    }
}

// ---------------------------------------------------------------------------
// Z[b,c] = (1/HW) * sum_m dot(dw[m,c,:], T[b,m,:]) + sum_m db[m,c].  Merged.
// ---------------------------------------------------------------------------
__global__ __launch_bounds__(256) void k_z(const float* __restrict__ T,
                                           const float* __restrict__ l_dw,
                                           const float* __restrict__ r_dw,
                                           const float* __restrict__ l_db,
                                           const float* __restrict__ r_db,
                                           float* __restrict__ Z) {
    int x = blockIdx.x;                        // 512: side*256 + b*64 + c
    int side = x >> 8, bc = x & 255;
    int b = bc >> 6, c = bc & 63;
    const float* dw = side ? r_dw : l_dw;
    const float* db = side ? r_db : l_db;
    int t = threadIdx.x, lane = t & 63, m = t >> 6;
    const float* wp = dw + (size_t)(m * 64 + c) * 576;
    const float* tp = T + side * 9216 + (size_t)(b * 4 + m) * 576;
    float s = 0.f;
    for (int j = lane; j < 576; j += 64) s += wp[j] * tp[j];
#pragma unroll
    for (int o = 32; o; o >>= 1) s += __shfl_xor(s, o, 64);
    __shared__ float red[4];
    if (lane == 0) red[m] = s;
    __syncthreads();
    if (t == 0) {
        float z = (red[0] + red[1]) + (red[2] + red[3]);
        float bias = db[c] + db[64 + c] + db[128 + c] + db[192 + c];
        Z[x] = z * (1.f / (float)HWp) + bias;
    }
}

// ---------------------------------------------------------------------------
// Selection MLP tail, merged: grid 8 = (side*4 + b).
// ---------------------------------------------------------------------------
__global__ __launch_bounds__(256) void k_sel2(const float* __restrict__ Z,
                                              const float* __restrict__ l_db,
                                              const float* __restrict__ r_db,
                                              const float* __restrict__ l_c1w,
                                              const float* __restrict__ r_c1w,
                                              const float* __restrict__ l_c1b,
                                              const float* __restrict__ r_c1b,
                                              const float* __restrict__ l_pw,
                                              const float* __restrict__ r_pw,
                                              float* __restrict__ Sw,
                                              float* __restrict__ Qb) {
    int x = blockIdx.x;                        // side*4 + b
    int side = x >> 2;
    const float* db  = side ? r_db  : l_db;
    const float* c1w = side ? r_c1w : l_c1w;
    const float* c1b = side ? r_c1b : l_c1b;
    const float* pw  = side ? r_pw  : l_pw;
    int t = threadIdx.x, lane = t & 63, wv = t >> 6;
    __shared__ float zs[64], ss[128], sw[256];
    __shared__ float cw[128 * 64];
    if (t < 64) zs[t] = Z[x * 64 + t];
    for (int i = t; i < 8192; i += 256) cw[i] = c1w[i];
    __syncthreads();
    if (t < 128) {
        float s = c1b[t];
        const float* wrow = cw + t * 64;
        for (int c = 0; c < 64; ++c) s += zs[c] * wrow[c];
        ss[t] = fmaxf(s, 0.f);
    }
    __syncthreads();
    float p = 0.f;
    for (int j = 0; j < 128; ++j) p += ss[j] * pw[j * 256 + t];
    float mx = p;
#pragma unroll
    for (int o = 32; o; o >>= 1) mx = fmaxf(mx, __shfl_xor(mx, o, 64));
    float e = __expf(p - mx);
    float sum = e;
#pragma unroll
    for (int o = 32; o; o >>= 1) sum += __shfl_xor(sum, o, 64);
    float swv = e / sum;
    Sw[(x * 4 + wv) * 64 + lane] = swv;
    sw[wv * 64 + lane] = swv;
    __syncthreads();
    if (t < 64) {
        float qb = sw[t] * db[t] + sw[64 + t] * db[64 + t]
                 + sw[128 + t] * db[128 + t] + sw[192 + t] * db[192 + t];
        Qb[x * 64 + t] = qb;
    }
}

// ---------------------------------------------------------------------------
// Fold Sw into conv weights, bf16, MFMA B-fragment order. Merged (4608 blks).
// ---------------------------------------------------------------------------
__global__ __launch_bounds__(256) void k_fold(const float* __restrict__ l_dw,
                                              const float* __restrict__ r_dw,
                                              const float* __restrict__ Sw,
                                              short* __restrict__ WB) {
    int bx = blockIdx.x;
    int side = (bx >= 2304) ? 1 : 0;
    int idx = (bx - side * 2304) * 256 + threadIdx.x;   // 589824 per side
    const float* dw = side ? r_dw : l_dw;
    short* wbs = WB + (size_t)side * 589824;
    int kk = idx & 31;
    int co = (idx >> 5) & 63;
    int rest = idx >> 11;            // [0,288)
    int tpair = rest % 18;
    int bc = rest / 18;              // [0,16)
    int chunk = bc & 3, b = bc >> 2;
    int tpl = kk >> 4, cil = kk & 15;
    int tap = 2 * tpair + tpl;
    int m = tap / 9, k9 = tap % 9;
    int ci = chunk * 16 + cil;
    float val = Sw[((side * 4 + b) * 4 + m) * 64 + co]
              * dw[(size_t)((m * 64 + co) * 64 + ci) * 9 + k9];
    wbs[idx] = f2bf(val);
}

// ---------------------------------------------------------------------------
// MFMA implicit-GEMM fused 4-dilation conv -> Q (bf16 NHWC).
// tp loop fully unrolled (R9): compile-time offsets, scheduler hoists the
// global weight loads across iterations with counted vmcnt.
// ---------------------------------------------------------------------------
__global__ __launch_bounds__(256) void k_convm(const short* __restrict__ XBl,
                                               const short* __restrict__ XBr,
                                               const short* __restrict__ WBa,
                                               const float* __restrict__ QBa,
                                               short* __restrict__ QLs,
                                               short* __restrict__ QRs) {
    const int wt = blockIdx.x, h = blockIdx.y;
    const int side = blockIdx.z >> 2, b = blockIdx.z & 3;
    const short* XB = side ? XBr : XBl;
    const short* WB = WBa + (size_t)side * 589824;
    const float* Qb = QBa + side * 256;
    short* Qs = side ? QRs : QLs;
    const int t = threadIdx.x;
    const int lane = t & 63, wave = t >> 6;
    const int g = lane >> 4, ln15 = lane & 15;
    __shared__ short tile[2 * 9 * 144 * 8];   // [half][r][col][ci8]

    f32x4 acc[2][4];
    {
        float qb[4];
#pragma unroll
        for (int nt = 0; nt < 4; ++nt) qb[nt] = Qb[b * 64 + nt * 16 + ln15];
#pragma unroll
        for (int mt = 0; mt < 2; ++mt)
#pragma unroll
            for (int nt = 0; nt < 4; ++nt)
                acc[mt][nt] = (f32x4){qb[nt], qb[nt], qb[nt], qb[nt]};
    }
    const int w0 = wt * 128;
    const int laneelem = (wave * 32 + ln15) * 8;
    const int halfoff = (g & 1) * (9 * 144 * 8);
    const int tsel = g >> 1;

    // register staging buffer: 6 slots x 2 halves
    short8 pv[6][2];
    auto LOADC = [&](int chunk) {
        const short* src = XB + (size_t)(b * 4 + chunk) * NH * NW * 16;
#pragma unroll
        for (int i = 0; i < 6; ++i) {
            const int slot = t + i * 256;
            const bool live = (i < 5) || (t < 16);   // 1296 = 5*256 + 16
            short8 z = {0, 0, 0, 0, 0, 0, 0, 0};
            pv[i][0] = z; pv[i][1] = z;
            if (live) {
                int r = slot / 144, col = slot % 144;
                int gh = h + 2 * r - 8;
                int gw = w0 - 8 + col;
                if (gh >= 0 && gh < NH && gw >= 0 && gw < NW) {
                    const short* p = src + ((size_t)gh * NW + gw) * 16;
                    pv[i][0] = *(const short8*)p;
                    pv[i][1] = *(const short8*)(p + 8);
                }
            }
        }
    };

    LOADC(0);
    for (int chunk = 0; chunk < 4; ++chunk) {
        __builtin_amdgcn_s_barrier();
        __builtin_amdgcn_sched_barrier(0);
#pragma unroll
        for (int i = 0; i < 6; ++i) {
            const int slot = t + i * 256;
            const bool live = (i < 5) || (t < 16);
            if (live) {
                *(short8*)(tile + slot * 8) = pv[i][0];
                *(short8*)(tile + (9 * 144 + slot) * 8) = pv[i][1];
            }
        }
        if (chunk < 3) LOADC(chunk + 1);   // prefetch: vmcnt stays in flight
        asm volatile("s_waitcnt lgkmcnt(0)" ::: "memory");  // ds_writes visible
        __builtin_amdgcn_s_barrier();      // tile ready
        __builtin_amdgcn_sched_barrier(0);

        const short* wbase = WB + (size_t)((b * 4 + chunk) * 18) * 2048 + ln15 * 32 + g * 8;
#pragma unroll
        for (int tp = 0; tp < 18; ++tp) {
            const int ta = 2 * tp, tb = ta + 1;
            const int ma = ta / 9, k9a = ta % 9;
            const int mb = tb / 9, k9b = tb % 9;
            const int offA = ((4 + (ma + 1) * (k9a / 3 - 1)) * 144 + 8 + 2 * (ma + 1) * (k9a % 3 - 1)) * 8;
            const int offB = ((4 + (mb + 1) * (k9b / 3 - 1)) * 144 + 8 + 2 * (mb + 1) * (k9b % 3 - 1)) * 8;
            const int aoff = (tsel ? offB : offA) + laneelem + halfoff;
            const short* bp = wbase + (size_t)tp * 2048;
            short8 b0 = *(const short8*)(bp);
            short8 b1 = *(const short8*)(bp + 512);
            short8 b2 = *(const short8*)(bp + 1024);
            short8 b3 = *(const short8*)(bp + 1536);
            const short* ap = tile + aoff;
            short8 a0 = *(const short8*)(ap);
            short8 a1 = *(const short8*)(ap + 128);
            acc[0][0] = __builtin_amdgcn_mfma_f32_16x16x32_bf16(a0, b0, acc[0][0], 0, 0, 0);
            acc[0][1] = __builtin_amdgcn_mfma_f32_16x16x32_bf16(a0, b1, acc[0][1], 0, 0, 0);
            acc[0][2] = __builtin_amdgcn_mfma_f32_16x16x32_bf16(a0, b2, acc[0][2], 0, 0, 0);
            acc[0][3] = __builtin_amdgcn_mfma_f32_16x16x32_bf16(a0, b3, acc[0][3], 0, 0, 0);
            acc[1][0] = __builtin_amdgcn_mfma_f32_16x16x32_bf16(a1, b0, acc[1][0], 0, 0, 0);
            acc[1][1] = __builtin_amdgcn_mfma_f32_16x16x32_bf16(a1, b1, acc[1][1], 0, 0, 0);
            acc[1][2] = __builtin_amdgcn_mfma_f32_16x16x32_bf16(a1, b2, acc[1][2], 0, 0, 0);
            acc[1][3] = __builtin_amdgcn_mfma_f32_16x16x32_bf16(a1, b3, acc[1][3], 0, 0, 0);
        }
    }
    // epilogue: D row=(lane>>4)*4+j (px), col=lane&15 (co); store bf16 NHWC
#pragma unroll
    for (int mt = 0; mt < 2; ++mt) {
        int px = w0 + wave * 32 + mt * 16 + g * 4;
#pragma unroll
        for (int j = 0; j < 4; ++j) {
            short* qp = Qs + ((size_t)(b * NH + h) * NW + px + j) * 64 + ln15;
            qp[0]  = f2bf(acc[mt][0][j]);
            qp[16] = f2bf(acc[mt][1][j]);
            qp[32] = f2bf(acc[mt][2][j]);
            qp[48] = f2bf(acc[mt][3][j]);
        }
    }
}

// ---------------------------------------------------------------------------
// Fused cross-attention, flash-style, both QK^T and PV on MFMA.
// Wave owns 32 q-rows; grid (4, NH, 2*NB) = 6144 blocks.
// ---------------------------------------------------------------------------
__global__ __launch_bounds__(128, 2) void k_attn(const short* __restrict__ QL,
                                                 const short* __restrict__ QR,
                                                 const short* __restrict__ VL,
                                                 const short* __restrict__ VR,
                                                 const float* __restrict__ x_l,
                                                 const float* __restrict__ x_r,
                                                 const float* __restrict__ beta,
                                                 const float* __restrict__ gamma,
                                                 float* __restrict__ out_all) {
    const int bx = blockIdx.x, h = blockIdx.y;
    const int side = blockIdx.z >> 2, b = blockIdx.z & 3;
    constexpr size_t PLANE = (size_t)NB * NC * NH * NW;
    const short* Qa  = side ? QR : QL;
    const short* Qbp = side ? QL : QR;
    const short* VT  = side ? VL : VR;
    const float* xres = side ? x_r : x_l;
    const float* scl  = side ? gamma : beta;
    float* out = out_all + (side ? PLANE : 0);

    const int t = threadIdx.x, lane = t & 63, wave = t >> 6;
    const int q = lane >> 4, c15 = lane & 15;
    __shared__ __align__(16) short PB[2][32 * 72];
    short* pb = PB[wave];

    const int wbase = bx * 64 + wave * 32;
    const short* qabase = Qa + ((size_t)(b * NH + h) * NW + wbase) * 64;
    const short* qbbase = Qbp + ((size_t)(b * NH + h) * NW) * 64;

    short8 afrag[2][2];
#pragma unroll
    for (int mt = 0; mt < 2; ++mt)
#pragma unroll
        for (int kk = 0; kk < 2; ++kk)
            afrag[mt][kk] = *(const short8*)(qabase + (mt * 16 + c15) * 64 + kk * 32 + q * 8);

    f32x4 osum[2][4];
#pragma unroll
    for (int mt = 0; mt < 2; ++mt)
#pragma unroll
        for (int nt = 0; nt < 4; ++nt) osum[mt][nt] = (f32x4){0.f, 0.f, 0.f, 0.f};
    float mrow[8], lrow[8];
#pragma unroll
    for (int i = 0; i < 8; ++i) { mrow[i] = -1e30f; lrow[i] = 0.f; }

    for (int vt = 0; vt < 4; ++vt) {
        f32x4 s[2][4];
#pragma unroll
        for (int mt = 0; mt < 2; ++mt)
#pragma unroll
            for (int nt = 0; nt < 4; ++nt) s[mt][nt] = (f32x4){0.f, 0.f, 0.f, 0.f};
#pragma unroll
        for (int kk = 0; kk < 2; ++kk) {
            short8 bq[4];
#pragma unroll
            for (int nt = 0; nt < 4; ++nt)
                bq[nt] = *(const short8*)(qbbase + (size_t)(vt * 64 + nt * 16 + c15) * 64 + kk * 32 + q * 8);
#pragma unroll
            for (int mt = 0; mt < 2; ++mt)
#pragma unroll
                for (int nt = 0; nt < 4; ++nt)
                    s[mt][nt] = __builtin_amdgcn_mfma_f32_16x16x32_bf16(afrag[mt][kk], bq[nt], s[mt][nt], 0, 0, 0);
        }
#pragma unroll
        for (int mt = 0; mt < 2; ++mt)
#pragma unroll
            for (int nt = 0; nt < 4; ++nt)
#pragma unroll
                for (int r = 0; r < 4; ++r) s[mt][nt][r] *= 0.125f;
        float al[8];
#pragma unroll
        for (int mt = 0; mt < 2; ++mt)
#pragma unroll
            for (int r = 0; r < 4; ++r) {
                float m0 = fmaxf(fmaxf(s[mt][0][r], s[mt][1][r]), fmaxf(s[mt][2][r], s[mt][3][r]));
#pragma unroll
                for (int msk = 1; msk < 16; msk <<= 1) m0 = fmaxf(m0, __shfl_xor(m0, msk, 64));
                int i = mt * 4 + r;
                float mn = fmaxf(mrow[i], m0);
                al[i] = __expf(mrow[i] - mn);
                mrow[i] = mn;
            }
#pragma unroll
        for (int mt = 0; mt < 2; ++mt)
#pragma unroll
            for (int r = 0; r < 4; ++r) {
                int i = mt * 4 + r;
                float m = mrow[i];
                float p0 = __expf(s[mt][0][r] - m);
                float p1 = __expf(s[mt][1][r] - m);
                float p2 = __expf(s[mt][2][r] - m);
                float p3 = __expf(s[mt][3][r] - m);
                short4t pk = {f2bf(p0), f2bf(p1), f2bf(p2), f2bf(p3)};
                *(short4t*)(pb + (mt * 16 + q * 4 + r) * 72 + c15 * 4) = pk;
                float lsv = (p0 + p1) + (p2 + p3);
#pragma unroll
                for (int msk = 1; msk < 16; msk <<= 1) lsv += __shfl_xor(lsv, msk, 64);
                lrow[i] = lrow[i] * al[i] + lsv;
            }
#pragma unroll
        for (int mt = 0; mt < 2; ++mt)
#pragma unroll
            for (int nt = 0; nt < 4; ++nt)
#pragma unroll
                for (int r = 0; r < 4; ++r) osum[mt][nt][r] *= al[mt * 4 + r];
#pragma unroll
        for (int kk = 0; kk < 2; ++kk) {
            short8 ap[2], bv[4];
#pragma unroll
            for (int mt = 0; mt < 2; ++mt)
                ap[mt] = *(const short8*)(pb + (mt * 16 + c15) * 72 + kk * 32 + q * 8);
#pragma unroll
            for (int nt = 0; nt < 4; ++nt)
                bv[nt] = *(const short8*)(VT + ((size_t)(b * 64 + nt * 16 + c15) * NH + h) * NW + vt * 64 + kk * 32 + q * 8);
#pragma unroll
            for (int mt = 0; mt < 2; ++mt)
#pragma unroll
                for (int nt = 0; nt < 4; ++nt)
                    osum[mt][nt] = __builtin_amdgcn_mfma_f32_16x16x32_bf16(ap[mt], bv[nt], osum[mt][nt], 0, 0, 0);
        }
    }
    float linv[8];
#pragma unroll
    for (int i = 0; i < 8; ++i) linv[i] = 1.f / lrow[i];
#pragma unroll
    for (int nt = 0; nt < 4; ++nt) {
        int c = nt * 16 + c15;
        float bv = scl[c];
        size_t pbase = ((size_t)(b * 64 + c) * NH + h) * NW + wbase;
#pragma unroll
        for (int mt = 0; mt < 2; ++mt)
#pragma unroll
            for (int r = 0; r < 4; ++r) {
                size_t o = pbase + mt * 16 + q * 4 + r;
                out[o] = xres[o] + osum[mt][nt][r] * linv[mt * 4 + r] * bv;
            }
    }
}

// ---------------------------------------------------------------------------
extern "C" void kernel_launch(void* const* d_in, const int* in_sizes, int n_in,
                              void* d_out, int out_size, void* d_ws, size_t ws_size,
                              hipStream_t stream) {
    const float* x_l   = (const float*)d_in[0];
    const float* x_r   = (const float*)d_in[1];
    const float* lnl_g = (const float*)d_in[2];
    const float* lnl_b = (const float*)d_in[3];
    const float* lnr_g = (const float*)d_in[4];
    const float* lnr_b = (const float*)d_in[5];
    const float* l_dw  = (const float*)d_in[6];
    const float* l_db  = (const float*)d_in[7];
    const float* l_c1w = (const float*)d_in[8];
    const float* l_c1b = (const float*)d_in[9];
    const float* l_pw  = (const float*)d_in[10];
    const float* r_dw  = (const float*)d_in[11];
    const float* r_db  = (const float*)d_in[12];
    const float* r_c1w = (const float*)d_in[13];
    const float* r_c1b = (const float*)d_in[14];
    const float* r_pw  = (const float*)d_in[15];
    const float* l2w   = (const float*)d_in[16];
    const float* l2b   = (const float*)d_in[17];
    const float* r2w   = (const float*)d_in[18];
    const float* r2b   = (const float*)d_in[19];
    const float* beta  = (const float*)d_in[20];
    const float* gamma = (const float*)d_in[21];
    float* out = (float*)d_out;

    constexpr size_t PLANE = (size_t)NB * NC * NH * NW;   // 6291456
    float* ws = (float*)d_ws;
    short* XBl = (short*)ws;         ws += PLANE / 2;     // bf16 [b][chunk][h][w][16]
    short* XBr = (short*)ws;         ws += PLANE / 2;
    short* QLs = (short*)ws;         ws += PLANE / 2;
    short* QRs = (short*)ws;         ws += PLANE / 2;
    short* VLs = (short*)ws;         ws += PLANE / 2;
    short* VRs = (short*)ws;         ws += PLANE / 2;
    short* WB  = (short*)ws;         ws += 589824;        // 2 x 589824 bf16
    float* Rb  = ws;                 ws += 442368;        // 2*4*64*96*9
    float* Tb  = ws;                 ws += 18432;
    float* SW  = ws;                 ws += 2048;
    float* QB  = ws;                 ws += 512;
    float* Zb  = ws;                 ws += 512;

    dim3 blk(256);
    // LN + V grid-fused (both depend only on inputs)
    k_lnv   <<<dim3(5, NH, 2 * NB), blk, 0, stream>>>(x_l, x_r, lnl_g, lnl_b, lnr_g, lnr_b,
                                                      XBl, XBr, Rb,
                                                      l2w, l2b, r2w, r2b, VLs, VRs);
    k_comb  <<<dim3(512), dim3(128), 0, stream>>>(Rb, Tb);
    k_z     <<<dim3(512), blk, 0, stream>>>(Tb, l_dw, r_dw, l_db, r_db, Zb);
    k_sel2  <<<dim3(8), blk, 0, stream>>>(Zb, l_db, r_db, l_c1w, r_c1w,
                                          l_c1b, r_c1b, l_pw, r_pw, SW, QB);
    k_fold  <<<dim3(4608), blk, 0, stream>>>(l_dw, r_dw, SW, WB);
    k_convm <<<dim3(2, NH, 2 * NB), blk, 0, stream>>>(XBl, XBr, WB, QB, QLs, QRs);
    k_attn  <<<dim3(4, NH, 2 * NB), dim3(128), 0, stream>>>(QLs, QRs, VLs, VRs,
                                                            x_l, x_r, beta, gamma, out);
}

// Round 6
// 315.474 us; speedup vs baseline: 1.8544x; 1.1868x over previous
//
#include <hip/hip_runtime.h>
#include <hip/hip_bf16.h>
#include <cstdint>

// Problem constants (B,C,H,W fixed by setup_inputs)
constexpr int NB = 4;
constexpr int NC = 64;
constexpr int NH = 96;
constexpr int NW = 256;
constexpr int HWp = NH * NW;          // 24576 pixels per plane
constexpr float EPS = 1e-6f;

typedef __attribute__((ext_vector_type(8))) short short8;
typedef __attribute__((ext_vector_type(4))) short short4t;
typedef __attribute__((ext_vector_type(4))) float f32x4;

static __device__ __forceinline__ short f2bf(float f) {
    __hip_bfloat16 h = __float2bfloat16(f);
    return *reinterpret_cast<short*>(&h);
}

// ---------------------------------------------------------------------------
// k_lnv = grid-fused LayerNorm(+rect row-sums) AND 1x1-conv V.
// blockIdx.x==4 -> LN path (768 blocks), else V path (3072 blocks).
// ---------------------------------------------------------------------------
__global__ __launch_bounds__(256) void k_lnv(const float* __restrict__ x_l,
                                             const float* __restrict__ x_r,
                                             const float* __restrict__ gl,
                                             const float* __restrict__ bl,
                                             const float* __restrict__ gr,
                                             const float* __restrict__ br,
                                             short* __restrict__ XBl,
                                             short* __restrict__ XBr,
                                             float* __restrict__ R,
                                             const float* __restrict__ w2l,
                                             const float* __restrict__ b2l,
                                             const float* __restrict__ w2r,
                                             const float* __restrict__ b2r,
                                             short* __restrict__ VL,
                                             short* __restrict__ VR) {
    __shared__ float smem[8704];               // union: LN 8192 / V 2x4352
    const int h = blockIdx.y, sideb = blockIdx.z;
    const int side = sideb >> 2, b = sideb & 3;
    const int t = threadIdx.x;

    if (blockIdx.x == 4) {
        // ================= LN + rect row-sums =================
        const float* x = side ? x_r : x_l;
        const float* g = side ? gr : gl;
        const float* bta = side ? br : bl;
        short* XB = side ? XBr : XBl;
        float* xm = smem;

        const float* xp = x + ((size_t)b * NC * NH + h) * NW + t;
        float v[64];
        float s = 0.f, sq = 0.f;
#pragma unroll
        for (int c = 0; c < 64; ++c) {
            float tv = xp[(size_t)c * HWp];
            v[c] = tv; s += tv; sq += tv * tv;
        }
        float mu = s * (1.f / 64.f);
        float var = sq * (1.f / 64.f) - mu * mu;
        float rs = rsqrtf(var + EPS);
#pragma unroll
        for (int c = 0; c < 64; ++c) v[c] = (v[c] - mu) * rs * g[c] + bta[c];

        // bf16 XB[b][chunk][h][w][16ci]
#pragma unroll
        for (int chunk = 0; chunk < 4; ++chunk) {
            short8 s0, s1;
#pragma unroll
            for (int j = 0; j < 8; ++j) {
                s0[j] = f2bf(v[chunk * 16 + j]);
                s1[j] = f2bf(v[chunk * 16 + 8 + j]);
            }
            short* xb = XB + (((size_t)(b * 4 + chunk) * NH + h) * NW + t) * 16;
            *(short8*)xb = s0;
            *(short8*)(xb + 8) = s1;
        }

        // Row-sum + edge partials via LDS transpose, 2 passes of 32 channels.
#pragma unroll
        for (int p = 0; p < 2; ++p) {
            const int cbase = p * 32;
            __syncthreads();
#pragma unroll
            for (int c = 0; c < 32; ++c)
                xm[c * 256 + (((t >> 2) ^ (c & 7)) << 2) + (t & 3)] = v[cbase + c];
            __syncthreads();
            const int cc = t & 31, q = t >> 5;
            float rsum = 0.f;
            float4 fs0 = {0,0,0,0}, fs1 = {0,0,0,0}, ls0 = {0,0,0,0}, ls1 = {0,0,0,0};
#pragma unroll
            for (int i = 0; i < 8; ++i) {
                int j4 = q * 8 + i;
                float4 f = *(const float4*)&xm[cc * 256 + ((j4 ^ (cc & 7)) << 2)];
                rsum += (f.x + f.y) + (f.z + f.w);
                if (i == 0) fs0 = f;
                if (i == 1) fs1 = f;
                if (i == 6) ls0 = f;
                if (i == 7) ls1 = f;
            }
            __syncthreads();
            xm[cc * 8 + q] = rsum;
            if (q == 7) {
                *(float4*)&xm[256 + cc * 8] = ls0;
                *(float4*)&xm[256 + cc * 8 + 4] = ls1;
            }
            __syncthreads();
            if (t < 32) {
                const int c = t;
                float full = 0.f;
#pragma unroll
                for (int q2 = 0; q2 < 8; ++q2) full += xm[c * 8 + q2];
                float h0 = xm[256 + c * 8 + 0], h1 = xm[256 + c * 8 + 1];
                float h2 = xm[256 + c * 8 + 2], h3 = xm[256 + c * 8 + 3];
                float h4 = xm[256 + c * 8 + 4], h5 = xm[256 + c * 8 + 5];
                float h6 = xm[256 + c * 8 + 6], h7 = xm[256 + c * 8 + 7];
                float e2 = fs0.x + fs0.y;
                float e4 = e2 + fs0.z + fs0.w;
                float e6 = e4 + fs1.x + fs1.y;
                float e8 = e6 + fs1.z + fs1.w;
                float r2 = h6 + h7;
                float r4 = (h4 + h5) + r2;
                float r6 = r4 + (h2 + h3);
                float r8 = r6 + (h0 + h1);
                float* Rp = R + ((size_t)(sideb * 64 + cbase + c) * NH + h) * 9;
                Rp[0] = full; Rp[1] = e2; Rp[2] = e4; Rp[3] = e6; Rp[4] = e8;
                Rp[5] = r2;  Rp[6] = r4; Rp[7] = r6; Rp[8] = r8;
            }
        }
    } else {
        // ================= 1x1 conv V =================
        const int wt = blockIdx.x;
        const float* x  = side ? x_r : x_l;
        const float* w2 = side ? w2r : w2l;
        const float* b2 = side ? b2r : b2l;
        short* VT = side ? VR : VL;
        const int lane = t & 63, q = t >> 6;
        float* xs  = smem;                     // [ci][px] then reused as [c][px]
        float* w2t = smem + 4352;              // [ci][c]
        int w0 = wt * 64;
        const float* src = x + (size_t)(b * 64) * HWp + h * NW + w0;
        for (int idx = t; idx < 4096; idx += 256) {
            int ci = idx >> 6, col = idx & 63;
            xs[ci * 68 + col] = src[(size_t)ci * HWp + col];
        }
        for (int idx = t; idx < 4096; idx += 256) {
            int co = idx >> 6, ci = idx & 63;
            w2t[ci * 68 + co] = w2[co * 64 + ci];
        }
        __syncthreads();

        const int pl0 = (lane & 15) * 4;
        const int c0 = q * 16 + (lane >> 4) * 4;
        f32x4 a4[4];
#pragma unroll
        for (int cc = 0; cc < 4; ++cc) {
            float bb = b2[c0 + cc];
            a4[cc] = (f32x4){bb, bb, bb, bb};
        }
        for (int ci = 0; ci < 64; ++ci) {
            f32x4 xv = *(const f32x4*)(xs + ci * 68 + pl0);
            f32x4 wv = *(const f32x4*)(w2t + ci * 68 + c0);
            a4[0] += xv * wv[0];
            a4[1] += xv * wv[1];
            a4[2] += xv * wv[2];
            a4[3] += xv * wv[3];
        }
        __syncthreads();
#pragma unroll
        for (int cc = 0; cc < 4; ++cc)
            *(f32x4*)(xs + (c0 + cc) * 68 + pl0) = a4[cc];
        __syncthreads();
        {
            int s = t & 63, g2 = t >> 6;
            int u = (s >> 2) + 16 * (s & 3);
#pragma unroll
            for (int cc = 0; cc < 16; ++cc) {
                int ch = g2 * 16 + cc;
                VT[((size_t)(b * 64 + ch) * NH + h) * NW + w0 + s] = f2bf(xs[ch * 68 + u]);
            }
        }
    }
}

// ---------------------------------------------------------------------------
// Combine per-row values into the 36 rect sums per (side,b,ci).
// ---------------------------------------------------------------------------
__global__ __launch_bounds__(128) void k_comb(const float* __restrict__ R,
                                              float* __restrict__ T) {
    int x = blockIdx.x;                        // side*256 + b*64 + ci
    int side = x >> 8, rem = x & 255, b = rem >> 6, ci = rem & 63;
    __shared__ float rp[NH][9];
    int t = threadIdx.x;
    const float* src = R + (size_t)x * NH * 9;
    for (int i = t; i < NH * 9; i += 128) ((float*)rp)[i] = src[i];
    __syncthreads();
    if (t < 36) {
        int m = t / 9, kh = (t % 9) / 3, kw = t % 3;
        int d = 2 * (m + 1);
        int r0 = (kh == 2) ? d : 0;
        int r1 = (kh == 0) ? NH - d : NH;
        float s = 0.f;
        for (int r = r0; r < r1; ++r) {
            float rowv = rp[r][0];
            if (kw == 0) rowv -= rp[r][5 + m];
            else if (kw == 2) rowv -= rp[r][1 + m];
            s += rowv;
        }
        T[side * 9216 + (b * 4 + m) * 576 + ci * 9 + kh * 3 + kw] = s;
    }
}

// ---------------------------------------------------------------------------
// Z[b,c] = (1/HW) * sum_m dot(dw[m,c,:], T[b,m,:]) + sum_m db[m,c].  Merged.
// ---------------------------------------------------------------------------
__global__ __launch_bounds__(256) void k_z(const float* __restrict__ T,
                                           const float* __restrict__ l_dw,
                                           const float* __restrict__ r_dw,
                                           const float* __restrict__ l_db,
                                           const float* __restrict__ r_db,
                                           float* __restrict__ Z) {
    int x = blockIdx.x;                        // 512: side*256 + b*64 + c
    int side = x >> 8, bc = x & 255;
    int b = bc >> 6, c = bc & 63;
    const float* dw = side ? r_dw : l_dw;
    const float* db = side ? r_db : l_db;
    int t = threadIdx.x, lane = t & 63, m = t >> 6;
    const float* wp = dw + (size_t)(m * 64 + c) * 576;
    const float* tp = T + side * 9216 + (size_t)(b * 4 + m) * 576;
    float s = 0.f;
    for (int j = lane; j < 576; j += 64) s += wp[j] * tp[j];
#pragma unroll
    for (int o = 32; o; o >>= 1) s += __shfl_xor(s, o, 64);
    __shared__ float red[4];
    if (lane == 0) red[m] = s;
    __syncthreads();
    if (t == 0) {
        float z = (red[0] + red[1]) + (red[2] + red[3]);
        float bias = db[c] + db[64 + c] + db[128 + c] + db[192 + c];
        Z[x] = z * (1.f / (float)HWp) + bias;
    }
}

// ---------------------------------------------------------------------------
// Selection MLP tail, merged: grid 8 = (side*4 + b).
// ---------------------------------------------------------------------------
__global__ __launch_bounds__(256) void k_sel2(const float* __restrict__ Z,
                                              const float* __restrict__ l_db,
                                              const float* __restrict__ r_db,
                                              const float* __restrict__ l_c1w,
                                              const float* __restrict__ r_c1w,
                                              const float* __restrict__ l_c1b,
                                              const float* __restrict__ r_c1b,
                                              const float* __restrict__ l_pw,
                                              const float* __restrict__ r_pw,
                                              float* __restrict__ Sw,
                                              float* __restrict__ Qb) {
    int x = blockIdx.x;                        // side*4 + b
    int side = x >> 2;
    const float* db  = side ? r_db  : l_db;
    const float* c1w = side ? r_c1w : l_c1w;
    const float* c1b = side ? r_c1b : l_c1b;
    const float* pw  = side ? r_pw  : l_pw;
    int t = threadIdx.x, lane = t & 63, wv = t >> 6;
    __shared__ float zs[64], ss[128], sw[256];
    __shared__ float cw[128 * 64];
    if (t < 64) zs[t] = Z[x * 64 + t];
    for (int i = t; i < 8192; i += 256) cw[i] = c1w[i];
    __syncthreads();
    if (t < 128) {
        float s = c1b[t];
        const float* wrow = cw + t * 64;
        for (int c = 0; c < 64; ++c) s += zs[c] * wrow[c];
        ss[t] = fmaxf(s, 0.f);
    }
    __syncthreads();
    float p = 0.f;
    for (int j = 0; j < 128; ++j) p += ss[j] * pw[j * 256 + t];
    float mx = p;
#pragma unroll
    for (int o = 32; o; o >>= 1) mx = fmaxf(mx, __shfl_xor(mx, o, 64));
    float e = __expf(p - mx);
    float sum = e;
#pragma unroll
    for (int o = 32; o; o >>= 1) sum += __shfl_xor(sum, o, 64);
    float swv = e / sum;
    Sw[(x * 4 + wv) * 64 + lane] = swv;
    sw[wv * 64 + lane] = swv;
    __syncthreads();
    if (t < 64) {
        float qb = sw[t] * db[t] + sw[64 + t] * db[64 + t]
                 + sw[128 + t] * db[128 + t] + sw[192 + t] * db[192 + t];
        Qb[x * 64 + t] = qb;
    }
}

// ---------------------------------------------------------------------------
// Fold Sw into conv weights, bf16, MFMA B-fragment order. Merged (4608 blks).
// ---------------------------------------------------------------------------
__global__ __launch_bounds__(256) void k_fold(const float* __restrict__ l_dw,
                                              const float* __restrict__ r_dw,
                                              const float* __restrict__ Sw,
                                              short* __restrict__ WB) {
    int bx = blockIdx.x;
    int side = (bx >= 2304) ? 1 : 0;
    int idx = (bx - side * 2304) * 256 + threadIdx.x;   // 589824 per side
    const float* dw = side ? r_dw : l_dw;
    short* wbs = WB + (size_t)side * 589824;
    int kk = idx & 31;
    int co = (idx >> 5) & 63;
    int rest = idx >> 11;            // [0,288)
    int tpair = rest % 18;
    int bc = rest / 18;              // [0,16)
    int chunk = bc & 3, b = bc >> 2;
    int tpl = kk >> 4, cil = kk & 15;
    int tap = 2 * tpair + tpl;
    int m = tap / 9, k9 = tap % 9;
    int ci = chunk * 16 + cil;
    float val = Sw[((side * 4 + b) * 4 + m) * 64 + co]
              * dw[(size_t)((m * 64 + co) * 64 + ci) * 9 + k9];
    wbs[idx] = f2bf(val);
}

// ---------------------------------------------------------------------------
// MFMA implicit-GEMM fused 4-dilation conv -> Q (bf16 NHWC).
// R11: co split ACROSS waves (not px). Wave w computes ALL 128 px x co
// quarter [16w,16w+16): acc[8][1]. Per tap-pair: ONE 16B/lane weight load
// (vs 4) + 8 ds_reads + 8 MFMA -> 8:1 MFMA:gload (R2's 4:1 ran 2x55.6us,
// R7's 2:1 ran 123us: the ratio is the binding variable). Block weight
// traffic drops 4x. pv staging dropped (null, R8; frees 48 VGPR).
// ---------------------------------------------------------------------------
__global__ __launch_bounds__(256) void k_convm(const short* __restrict__ XBl,
                                               const short* __restrict__ XBr,
                                               const short* __restrict__ WBa,
                                               const float* __restrict__ QBa,
                                               short* __restrict__ QLs,
                                               short* __restrict__ QRs) {
    const int wt = blockIdx.x, h = blockIdx.y;
    const int side = blockIdx.z >> 2, b = blockIdx.z & 3;
    const short* XB = side ? XBr : XBl;
    const short* WB = WBa + (size_t)side * 589824;
    const float* Qb = QBa + side * 256;
    short* Qs = side ? QRs : QLs;
    const int t = threadIdx.x;
    const int lane = t & 63, wave = t >> 6;
    const int g = lane >> 4, ln15 = lane & 15;
    __shared__ short tile[2 * 9 * 144 * 8];   // [half][r][col][ci8]

    f32x4 acc[8];
    {
        float qb = Qb[b * 64 + wave * 16 + ln15];
#pragma unroll
        for (int mt = 0; mt < 8; ++mt)
            acc[mt] = (f32x4){qb, qb, qb, qb};
    }
    const int w0 = wt * 128;
    const int halfoff = (g & 1) * (9 * 144 * 8);
    const int tsel = g >> 1;

    for (int chunk = 0; chunk < 4; ++chunk) {
        __syncthreads();                       // prior chunk's reads done
        const short* src = XB + (size_t)(b * 4 + chunk) * NH * NW * 16;
        for (int slot = t; slot < 9 * 144; slot += 256) {
            int r = slot / 144, col = slot % 144;
            int gh = h + 2 * r - 8;
            int gw = w0 - 8 + col;
            short8 v0 = {0, 0, 0, 0, 0, 0, 0, 0};
            short8 v1 = {0, 0, 0, 0, 0, 0, 0, 0};
            if (gh >= 0 && gh < NH && gw >= 0 && gw < NW) {
                const short* p = src + ((size_t)gh * NW + gw) * 16;
                v0 = *(const short8*)p;
                v1 = *(const short8*)(p + 8);
            }
            *(short8*)(tile + slot * 8) = v0;                 // ci 0..7
            *(short8*)(tile + (9 * 144 + slot) * 8) = v1;     // ci 8..15
        }
        __syncthreads();

        // wave's private weight stream: 1KB per tap-pair (16 co x 32 k)
        const short* wbase = WB + (size_t)((b * 4 + chunk) * 18) * 2048
                           + wave * 512 + ln15 * 32 + g * 8;
#pragma unroll
        for (int tp = 0; tp < 18; ++tp) {
            const int ta = 2 * tp, tb = ta + 1;
            const int ma = ta / 9, k9a = ta % 9;
            const int mb = tb / 9, k9b = tb % 9;
            const int offA = ((4 + (ma + 1) * (k9a / 3 - 1)) * 144 + 8 + 2 * (ma + 1) * (k9a % 3 - 1)) * 8;
            const int offB = ((4 + (mb + 1) * (k9b / 3 - 1)) * 144 + 8 + 2 * (mb + 1) * (k9b % 3 - 1)) * 8;
            const int aoff = (tsel ? offB : offA) + ln15 * 8 + halfoff;
            short8 bf = *(const short8*)(wbase + (size_t)tp * 2048);
            const short* ap = tile + aoff;
            short8 a0 = *(const short8*)(ap);
            short8 a1 = *(const short8*)(ap + 128);
            short8 a2 = *(const short8*)(ap + 256);
            short8 a3 = *(const short8*)(ap + 384);
            short8 a4 = *(const short8*)(ap + 512);
            short8 a5 = *(const short8*)(ap + 640);
            short8 a6 = *(const short8*)(ap + 768);
            short8 a7 = *(const short8*)(ap + 896);
            acc[0] = __builtin_amdgcn_mfma_f32_16x16x32_bf16(a0, bf, acc[0], 0, 0, 0);
            acc[1] = __builtin_amdgcn_mfma_f32_16x16x32_bf16(a1, bf, acc[1], 0, 0, 0);
            acc[2] = __builtin_amdgcn_mfma_f32_16x16x32_bf16(a2, bf, acc[2], 0, 0, 0);
            acc[3] = __builtin_amdgcn_mfma_f32_16x16x32_bf16(a3, bf, acc[3], 0, 0, 0);
            acc[4] = __builtin_amdgcn_mfma_f32_16x16x32_bf16(a4, bf, acc[4], 0, 0, 0);
            acc[5] = __builtin_amdgcn_mfma_f32_16x16x32_bf16(a5, bf, acc[5], 0, 0, 0);
            acc[6] = __builtin_amdgcn_mfma_f32_16x16x32_bf16(a6, bf, acc[6], 0, 0, 0);
            acc[7] = __builtin_amdgcn_mfma_f32_16x16x32_bf16(a7, bf, acc[7], 0, 0, 0);
        }
    }
    // epilogue: D row=(lane>>4)*4+j (px within 16-block), col=lane&15 (co
    // within wave's quarter); store bf16 NHWC at co = wave*16 + ln15.
#pragma unroll
    for (int mt = 0; mt < 8; ++mt) {
        int px = w0 + mt * 16 + g * 4;
#pragma unroll
        for (int j = 0; j < 4; ++j) {
            Qs[((size_t)(b * NH + h) * NW + px + j) * 64 + wave * 16 + ln15]
                = f2bf(acc[mt][j]);
        }
    }
}

// ---------------------------------------------------------------------------
// Fused cross-attention, flash-style, both QK^T and PV on MFMA.
// Wave owns 32 q-rows; grid (4, NH, 2*NB) = 6144 blocks.
// ---------------------------------------------------------------------------
__global__ __launch_bounds__(128, 2) void k_attn(const short* __restrict__ QL,
                                                 const short* __restrict__ QR,
                                                 const short* __restrict__ VL,
                                                 const short* __restrict__ VR,
                                                 const float* __restrict__ x_l,
                                                 const float* __restrict__ x_r,
                                                 const float* __restrict__ beta,
                                                 const float* __restrict__ gamma,
                                                 float* __restrict__ out_all) {
    const int bx = blockIdx.x, h = blockIdx.y;
    const int side = blockIdx.z >> 2, b = blockIdx.z & 3;
    constexpr size_t PLANE = (size_t)NB * NC * NH * NW;
    const short* Qa  = side ? QR : QL;
    const short* Qbp = side ? QL : QR;
    const short* VT  = side ? VL : VR;
    const float* xres = side ? x_r : x_l;
    const float* scl  = side ? gamma : beta;
    float* out = out_all + (side ? PLANE : 0);

    const int t = threadIdx.x, lane = t & 63, wave = t >> 6;
    const int q = lane >> 4, c15 = lane & 15;
    __shared__ __align__(16) short PB[2][32 * 72];
    short* pb = PB[wave];

    const int wbase = bx * 64 + wave * 32;
    const short* qabase = Qa + ((size_t)(b * NH + h) * NW + wbase) * 64;
    const short* qbbase = Qbp + ((size_t)(b * NH + h) * NW) * 64;

    short8 afrag[2][2];
#pragma unroll
    for (int mt = 0; mt < 2; ++mt)
#pragma unroll
        for (int kk = 0; kk < 2; ++kk)
            afrag[mt][kk] = *(const short8*)(qabase + (mt * 16 + c15) * 64 + kk * 32 + q * 8);

    f32x4 osum[2][4];
#pragma unroll
    for (int mt = 0; mt < 2; ++mt)
#pragma unroll
        for (int nt = 0; nt < 4; ++nt) osum[mt][nt] = (f32x4){0.f, 0.f, 0.f, 0.f};
    float mrow[8], lrow[8];
#pragma unroll
    for (int i = 0; i < 8; ++i) { mrow[i] = -1e30f; lrow[i] = 0.f; }

    for (int vt = 0; vt < 4; ++vt) {
        f32x4 s[2][4];
#pragma unroll
        for (int mt = 0; mt < 2; ++mt)
#pragma unroll
            for (int nt = 0; nt < 4; ++nt) s[mt][nt] = (f32x4){0.f, 0.f, 0.f, 0.f};
#pragma unroll
        for (int kk = 0; kk < 2; ++kk) {
            short8 bq[4];
#pragma unroll
            for (int nt = 0; nt < 4; ++nt)
                bq[nt] = *(const short8*)(qbbase + (size_t)(vt * 64 + nt * 16 + c15) * 64 + kk * 32 + q * 8);
#pragma unroll
            for (int mt = 0; mt < 2; ++mt)
#pragma unroll
                for (int nt = 0; nt < 4; ++nt)
                    s[mt][nt] = __builtin_amdgcn_mfma_f32_16x16x32_bf16(afrag[mt][kk], bq[nt], s[mt][nt], 0, 0, 0);
        }
#pragma unroll
        for (int mt = 0; mt < 2; ++mt)
#pragma unroll
            for (int nt = 0; nt < 4; ++nt)
#pragma unroll
                for (int r = 0; r < 4; ++r) s[mt][nt][r] *= 0.125f;
        float al[8];
#pragma unroll
        for (int mt = 0; mt < 2; ++mt)
#pragma unroll
            for (int r = 0; r < 4; ++r) {
                float m0 = fmaxf(fmaxf(s[mt][0][r], s[mt][1][r]), fmaxf(s[mt][2][r], s[mt][3][r]));
#pragma unroll
                for (int msk = 1; msk < 16; msk <<= 1) m0 = fmaxf(m0, __shfl_xor(m0, msk, 64));
                int i = mt * 4 + r;
                float mn = fmaxf(mrow[i], m0);
                al[i] = __expf(mrow[i] - mn);
                mrow[i] = mn;
            }
#pragma unroll
        for (int mt = 0; mt < 2; ++mt)
#pragma unroll
            for (int r = 0; r < 4; ++r) {
                int i = mt * 4 + r;
                float m = mrow[i];
                float p0 = __expf(s[mt][0][r] - m);
                float p1 = __expf(s[mt][1][r] - m);
                float p2 = __expf(s[mt][2][r] - m);
                float p3 = __expf(s[mt][3][r] - m);
                short4t pk = {f2bf(p0), f2bf(p1), f2bf(p2), f2bf(p3)};
                *(short4t*)(pb + (mt * 16 + q * 4 + r) * 72 + c15 * 4) = pk;
                float lsv = (p0 + p1) + (p2 + p3);
#pragma unroll
                for (int msk = 1; msk < 16; msk <<= 1) lsv += __shfl_xor(lsv, msk, 64);
                lrow[i] = lrow[i] * al[i] + lsv;
            }
#pragma unroll
        for (int mt = 0; mt < 2; ++mt)
#pragma unroll
            for (int nt = 0; nt < 4; ++nt)
#pragma unroll
                for (int r = 0; r < 4; ++r) osum[mt][nt][r] *= al[mt * 4 + r];
#pragma unroll
        for (int kk = 0; kk < 2; ++kk) {
            short8 ap[2], bv[4];
#pragma unroll
            for (int mt = 0; mt < 2; ++mt)
                ap[mt] = *(const short8*)(pb + (mt * 16 + c15) * 72 + kk * 32 + q * 8);
#pragma unroll
            for (int nt = 0; nt < 4; ++nt)
                bv[nt] = *(const short8*)(VT + ((size_t)(b * 64 + nt * 16 + c15) * NH + h) * NW + vt * 64 + kk * 32 + q * 8);
#pragma unroll
            for (int mt = 0; mt < 2; ++mt)
#pragma unroll
                for (int nt = 0; nt < 4; ++nt)
                    osum[mt][nt] = __builtin_amdgcn_mfma_f32_16x16x32_bf16(ap[mt], bv[nt], osum[mt][nt], 0, 0, 0);
        }
    }
    float linv[8];
#pragma unroll
    for (int i = 0; i < 8; ++i) linv[i] = 1.f / lrow[i];
#pragma unroll
    for (int nt = 0; nt < 4; ++nt) {
        int c = nt * 16 + c15;
        float bv = scl[c];
        size_t pbase = ((size_t)(b * 64 + c) * NH + h) * NW + wbase;
#pragma unroll
        for (int mt = 0; mt < 2; ++mt)
#pragma unroll
            for (int r = 0; r < 4; ++r) {
                size_t o = pbase + mt * 16 + q * 4 + r;
                out[o] = xres[o] + osum[mt][nt][r] * linv[mt * 4 + r] * bv;
            }
    }
}

// ---------------------------------------------------------------------------
extern "C" void kernel_launch(void* const* d_in, const int* in_sizes, int n_in,
                              void* d_out, int out_size, void* d_ws, size_t ws_size,
                              hipStream_t stream) {
    const float* x_l   = (const float*)d_in[0];
    const float* x_r   = (const float*)d_in[1];
    const float* lnl_g = (const float*)d_in[2];
    const float* lnl_b = (const float*)d_in[3];
    const float* lnr_g = (const float*)d_in[4];
    const float* lnr_b = (const float*)d_in[5];
    const float* l_dw  = (const float*)d_in[6];
    const float* l_db  = (const float*)d_in[7];
    const float* l_c1w = (const float*)d_in[8];
    const float* l_c1b = (const float*)d_in[9];
    const float* l_pw  = (const float*)d_in[10];
    const float* r_dw  = (const float*)d_in[11];
    const float* r_db  = (const float*)d_in[12];
    const float* r_c1w = (const float*)d_in[13];
    const float* r_c1b = (const float*)d_in[14];
    const float* r_pw  = (const float*)d_in[15];
    const float* l2w   = (const float*)d_in[16];
    const float* l2b   = (const float*)d_in[17];
    const float* r2w   = (const float*)d_in[18];
    const float* r2b   = (const float*)d_in[19];
    const float* beta  = (const float*)d_in[20];
    const float* gamma = (const float*)d_in[21];
    float* out = (float*)d_out;

    constexpr size_t PLANE = (size_t)NB * NC * NH * NW;   // 6291456
    float* ws = (float*)d_ws;
    short* XBl = (short*)ws;         ws += PLANE / 2;     // bf16 [b][chunk][h][w][16]
    short* XBr = (short*)ws;         ws += PLANE / 2;
    short* QLs = (short*)ws;         ws += PLANE / 2;
    short* QRs = (short*)ws;         ws += PLANE / 2;
    short* VLs = (short*)ws;         ws += PLANE / 2;
    short* VRs = (short*)ws;         ws += PLANE / 2;
    short* WB  = (short*)ws;         ws += 589824;        // 2 x 589824 bf16
    float* Rb  = ws;                 ws += 442368;        // 2*4*64*96*9
    float* Tb  = ws;                 ws += 18432;
    float* SW  = ws;                 ws += 2048;
    float* QB  = ws;                 ws += 512;
    float* Zb  = ws;                 ws += 512;

    dim3 blk(256);
    // LN + V grid-fused (both depend only on inputs)
    k_lnv   <<<dim3(5, NH, 2 * NB), blk, 0, stream>>>(x_l, x_r, lnl_g, lnl_b, lnr_g, lnr_b,
                                                      XBl, XBr, Rb,
                                                      l2w, l2b, r2w, r2b, VLs, VRs);
    k_comb  <<<dim3(512), dim3(128), 0, stream>>>(Rb, Tb);
    k_z     <<<dim3(512), blk, 0, stream>>>(Tb, l_dw, r_dw, l_db, r_db, Zb);
    k_sel2  <<<dim3(8), blk, 0, stream>>>(Zb, l_db, r_db, l_c1w, r_c1w,
                                          l_c1b, r_c1b, l_pw, r_pw, SW, QB);
    k_fold  <<<dim3(4608), blk, 0, stream>>>(l_dw, r_dw, SW, WB);
    k_convm <<<dim3(2, NH, 2 * NB), blk, 0, stream>>>(XBl, XBr, WB, QB, QLs, QRs);
    k_attn  <<<dim3(4, NH, 2 * NB), dim3(128), 0, stream>>>(QLs, QRs, VLs, VRs,
                                                            x_l, x_r, beta, gamma, out);
}